// Round 1
// baseline (58.201 us; speedup 1.0000x reference)
//
#include <hip/hip_runtime.h>
#include <hip/hip_bf16.h>

// pooled[b,i,ho] = bias[ho] + sum_{j!=i} W[ho, cell(b,i,j)*128 + h] * hidden[b,j,h]
// Plan:
//   K1: Y[b,j,c,ho] = sum_h hidden[b,j,h] * W[ho, c*128+h]   (dense bf16 MFMA GEMM)
//       A = hidden [4096 x 128], B[k][n=c*128+ho] = W[ho][c*128+k], Y bf16 [4096 x 8192]
//   K2: pooled[b,i,ho] = bias[ho] + sum_{j!=i} Y[b,j,cell(b,i,j),ho]   (gather-sum)
// Chunked over batches so only ws_size >= 1 MiB is required.

typedef __attribute__((ext_vector_type(8))) short bf16x8;
typedef __attribute__((ext_vector_type(4))) float f32x4;

#define LDPAD 136  // 128 + 8 bf16 pad: row stride 272B -> bank offset 4/row, 2-way max (free)

__global__ __launch_bounds__(256)
void gp_gemm(const float* __restrict__ hid,   // [4096, 128] (row0 offsets into it)
             const float* __restrict__ W,     // [128, 8192]
             __hip_bfloat16* __restrict__ Y,  // chunk: [bc*64, 8192]
             int row0)
{
    __shared__ __hip_bfloat16 As[64][LDPAD];
    __shared__ __hip_bfloat16 Bs[128][LDPAD];

    const int tid  = threadIdx.x;
    const int mblk = blockIdx.x;   // 64 rows of A per block == one batch
    const int c    = blockIdx.y;   // grid cell == n-block of 128 (c*128+ho)

    // ---- stage A tile: 64 x 128 f32 -> bf16 LDS ----
    const float* Ab = hid + (size_t)(row0 + mblk * 64) * 128;
    #pragma unroll
    for (int it = 0; it < 8; ++it) {
        int idx = it * 256 + tid;          // 0..2047, one float4 each
        int r = idx >> 5, k4 = idx & 31;
        float4 v = *(const float4*)(Ab + r * 128 + k4 * 4);
        __hip_bfloat16* d = &As[r][k4 * 4];
        d[0] = __float2bfloat16(v.x);
        d[1] = __float2bfloat16(v.y);
        d[2] = __float2bfloat16(v.z);
        d[3] = __float2bfloat16(v.w);
    }
    // ---- stage B tile: W[:, c*128 .. c*128+128] stored as Bs[n=ho][k] ----
    const float* Bb = W + (size_t)c * 128;
    #pragma unroll
    for (int it = 0; it < 16; ++it) {
        int idx = it * 256 + tid;          // 0..4095
        int r = idx >> 5, k4 = idx & 31;
        float4 v = *(const float4*)(Bb + (size_t)r * 8192 + k4 * 4);
        __hip_bfloat16* d = &Bs[r][k4 * 4];
        d[0] = __float2bfloat16(v.x);
        d[1] = __float2bfloat16(v.y);
        d[2] = __float2bfloat16(v.z);
        d[3] = __float2bfloat16(v.w);
    }
    __syncthreads();

    // ---- MFMA: wave w computes rows [w*16, w*16+16) x all 128 n ----
    const int w = tid >> 6, lane = tid & 63;
    const int lr = lane & 15, kg = lane >> 4;   // A row / B col ; k-group
    f32x4 acc[8];
    #pragma unroll
    for (int nt = 0; nt < 8; ++nt) acc[nt] = (f32x4){0.f, 0.f, 0.f, 0.f};
    #pragma unroll
    for (int ks = 0; ks < 4; ++ks) {
        bf16x8 a = *(const bf16x8*)&As[w * 16 + lr][ks * 32 + kg * 8];
        #pragma unroll
        for (int nt = 0; nt < 8; ++nt) {
            bf16x8 b = *(const bf16x8*)&Bs[nt * 16 + lr][ks * 32 + kg * 8];
            acc[nt] = __builtin_amdgcn_mfma_f32_16x16x32_bf16(a, b, acc[nt], 0, 0, 0);
        }
    }

    // ---- write Y tile (bf16). D layout: col=lane&15, row=(lane>>4)*4+r ----
    __hip_bfloat16* Yb = Y + (size_t)mblk * 64 * 8192 + (size_t)c * 128;
    #pragma unroll
    for (int nt = 0; nt < 8; ++nt) {
        #pragma unroll
        for (int r = 0; r < 4; ++r) {
            int m = w * 16 + kg * 4 + r;
            Yb[(size_t)m * 8192 + nt * 16 + lr] = __float2bfloat16(acc[nt][r]);
        }
    }
}

__global__ __launch_bounds__(128)
void gp_gather(const float* __restrict__ pos,       // [64, 64, 2] (full)
               const __hip_bfloat16* __restrict__ Y,// chunk: [bc*64, 8192]
               const float* __restrict__ bias,      // [128]
               float* __restrict__ out,             // [4096, 128] (full)
               int b0)
{
    __shared__ float px[64], py[64];
    __shared__ int cellj[64];
    const int tid = threadIdx.x;        // == ho
    const int blk = blockIdx.x;
    const int bl = blk >> 6, i = blk & 63;
    const int b = b0 + bl;

    if (tid < 64) {
        px[tid] = pos[((size_t)b * 64 + tid) * 2 + 0];
        py[tid] = pos[((size_t)b * 64 + tid) * 2 + 1];
    }
    __syncthreads();
    if (tid < 64) {
        // rel = pos[j] - pos[i]; gx = trunc((rel.x + 2) * 2) clipped to [0,7]
        float rx = px[tid] - px[i];
        float ry = py[tid] - py[i];
        int gx = (int)((rx + 2.0f) * 2.0f);
        int gy = (int)((ry + 2.0f) * 2.0f);
        gx = gx < 0 ? 0 : (gx > 7 ? 7 : gx);
        gy = gy < 0 ? 0 : (gy > 7 ? 7 : gy);
        cellj[tid] = (tid == i) ? -1 : (gx * 8 + gy);
    }
    __syncthreads();

    float acc = bias[tid];
    const __hip_bfloat16* Yb = Y + (size_t)bl * 64 * 8192;
    #pragma unroll 8
    for (int j = 0; j < 64; ++j) {
        int cj = cellj[j];
        if (cj >= 0) acc += __bfloat162float(Yb[(size_t)j * 8192 + cj * 128 + tid]);
    }
    out[((size_t)(b * 64 + i)) * 128 + tid] = acc;
}

extern "C" void kernel_launch(void* const* d_in, const int* in_sizes, int n_in,
                              void* d_out, int out_size, void* d_ws, size_t ws_size,
                              hipStream_t stream)
{
    const float* hid  = (const float*)d_in[0];  // [64,64,128]
    const float* pos  = (const float*)d_in[1];  // [64,64,2]
    const float* W    = (const float*)d_in[2];  // [128,8192]
    const float* bias = (const float*)d_in[3];  // [128]
    float* out = (float*)d_out;
    __hip_bfloat16* Y = (__hip_bfloat16*)d_ws;

    const size_t per_batch = (size_t)64 * 8192 * sizeof(__hip_bfloat16); // 1 MiB
    int Bc = (int)(ws_size / per_batch);
    if (Bc > 64) Bc = 64;
    if (Bc < 1) Bc = 1;  // requires ws_size >= 1 MiB

    for (int b0 = 0; b0 < 64; b0 += Bc) {
        int bc = (64 - b0 < Bc) ? (64 - b0) : Bc;
        dim3 g1(bc, 64);
        hipLaunchKernelGGL(gp_gemm, g1, dim3(256), 0, stream, hid, W, Y, b0 * 64);
        hipLaunchKernelGGL(gp_gather, dim3(bc * 64), dim3(128), 0, stream,
                           pos, Y, bias, out, b0);
    }
}

// Round 2
// 35.508 us; speedup vs baseline: 1.6391x; 1.6391x over previous
//
#include <hip/hip_runtime.h>
#include <hip/hip_bf16.h>
#include <stdint.h>

// pooled[b,i,:] = bias + sum_{j!=i} W_cell(b,i,j) . hid[b,j,:]
// Fused per (batch, cell-chunk):
//   Z_c  = hid_b (64x128) @ W_c^T (128x128)   -> LDS (bf16)
//   acc += M_c (64x64, 0/1) @ Z_c             -> VGPR f32
// No 67MB intermediate in HBM. W pre-converted to bf16 in ws, layout
// [c][h/8][ho][8] so per-c staging is one linear 32KB global_load_lds and all
// LDS fragment reads are lane-contiguous (conflict-free).

typedef __attribute__((ext_vector_type(8))) short bf16x8;
typedef __attribute__((ext_vector_type(4))) float f32x4;

#define NCHUNK 8   // cell chunks -> 64*NCHUNK blocks
#define CPB 8      // cells per block (64/NCHUNK)

__device__ inline void load_lds16(const void* g, void* l) {
    __builtin_amdgcn_global_load_lds(
        (const __attribute__((address_space(1))) unsigned int*)g,
        (__attribute__((address_space(3))) unsigned int*)l, 16, 0, 0);
}

__device__ inline unsigned short bf16bits(float x) {
    __hip_bfloat16 h = __float2bfloat16(x);
    return *reinterpret_cast<unsigned short*>(&h);
}

// ---- P1: W f32 [128][8192] -> Wb bf16 [c=64][hg=16][ho=128][e=8] ----
__global__ __launch_bounds__(512)
void gp_wconv(const float* __restrict__ W, __hip_bfloat16* __restrict__ Wb)
{
    __shared__ __attribute__((aligned(16))) __hip_bfloat16 Wl[128][136]; // [ho][h], +8 pad
    const int c = blockIdx.x, t = threadIdx.x;
    #pragma unroll
    for (int q = 0; q < 8; ++q) {
        int flat = q * 512 + t;            // coalesced read of W[:, c*128..+128]
        int ho = flat >> 5, k4 = flat & 31;
        float4 v = *(const float4*)(W + (size_t)ho * 8192 + c * 128 + k4 * 4);
        __hip_bfloat16* d = &Wl[ho][k4 * 4];
        d[0] = __float2bfloat16(v.x); d[1] = __float2bfloat16(v.y);
        d[2] = __float2bfloat16(v.z); d[3] = __float2bfloat16(v.w);
    }
    __syncthreads();
    #pragma unroll
    for (int q = 0; q < 4; ++q) {
        int flat = q * 512 + t;            // flat = hg*128 + ho
        int hg = flat >> 7, ho = flat & 127;
        bf16x8 v = *(const bf16x8*)&Wl[ho][hg * 8];
        *(bf16x8*)(Wb + (size_t)c * 16384 + (size_t)flat * 8) = v; // coalesced
    }
}

// ---- main fused kernel: grid = NCHUNK*64, block = 512 (8 waves) ----
__global__ __launch_bounds__(512, 4)
void gp_main(const float* __restrict__ hid, const float* __restrict__ pos,
             const __hip_bfloat16* __restrict__ Wb, float* __restrict__ partial)
{
    __shared__ __attribute__((aligned(16))) __hip_bfloat16 Ws[16 * 128 * 8]; // [hg][ho][e] 32KB
    __shared__ __attribute__((aligned(16))) __hip_bfloat16 Hs[16 * 64 * 8];  // [hg][j][e]  16KB
    __shared__ __attribute__((aligned(16))) __hip_bfloat16 Zt[8 * 128 * 8];  // [jg][ho][e] 16KB
    __shared__ __attribute__((aligned(16))) __hip_bfloat16 Ms[8 * 64 * 8];   // [jg][i][e]   8KB
    __shared__ unsigned char cellt[64 * 64];                                 // [i][j]       4KB
    __shared__ float ps[128];                                                // pos[b]      .5KB

    const int t = threadIdx.x;
    const int b = blockIdx.x & 63, chunk = blockIdx.x >> 6;
    const int w = t >> 6, lane = t & 63;
    const int l15 = lane & 15, kg = lane >> 4;   // 16x16x32 frag: row/col=l15, k-group=kg
    const int mw = w & 1, nw = w >> 1;           // wave tile: rows mw*32.., cols nw*32..

    if (t < 128) ps[t] = pos[(size_t)b * 128 + t];
    __syncthreads();

    // cell table (exactly matches reference: trunc-toward-zero, clip, gx-major)
    #pragma unroll
    for (int q = 0; q < 8; ++q) {
        int idx = q * 512 + t;
        int i = idx >> 6, j = idx & 63;
        float rx = ps[j * 2 + 0] - ps[i * 2 + 0];
        float ry = ps[j * 2 + 1] - ps[i * 2 + 1];
        int gx = (int)((rx + 2.0f) * 2.0f);
        int gy = (int)((ry + 2.0f) * 2.0f);
        gx = gx < 0 ? 0 : (gx > 7 ? 7 : gx);
        gy = gy < 0 ? 0 : (gy > 7 ? 7 : gy);
        cellt[idx] = (i == j) ? 255 : (unsigned char)(gx * 8 + gy);
    }
    // stage hid[b] -> Hs [hg][j][e] (LDS writes lane-contiguous)
    #pragma unroll
    for (int q = 0; q < 2; ++q) {
        int idx = q * 512 + t;
        int hg = idx >> 6, j = idx & 63;
        const float* src = hid + ((size_t)b * 64 + j) * 128 + hg * 8;
        float4 v0 = *(const float4*)src;
        float4 v1 = *(const float4*)(src + 4);
        __hip_bfloat16* d = &Hs[(hg * 64 + j) * 8];
        d[0] = __float2bfloat16(v0.x); d[1] = __float2bfloat16(v0.y);
        d[2] = __float2bfloat16(v0.z); d[3] = __float2bfloat16(v0.w);
        d[4] = __float2bfloat16(v1.x); d[5] = __float2bfloat16(v1.y);
        d[6] = __float2bfloat16(v1.z); d[7] = __float2bfloat16(v1.w);
    }

    f32x4 acc[2][2];
    #pragma unroll
    for (int fm = 0; fm < 2; ++fm)
        #pragma unroll
        for (int fn = 0; fn < 2; ++fn)
            acc[fm][fn] = (f32x4){0.f, 0.f, 0.f, 0.f};

    for (int cc = 0; cc < CPB; ++cc) {
        const int c = chunk * CPB + cc;
        __syncthreads();                       // A: prev acc-phase done
        // stage Ws for this c (linear 32KB, async)
        const char* gsrc = (const char*)(Wb + (size_t)c * 16384);
        #pragma unroll
        for (int r = 0; r < 4; ++r) {
            int off = r * 8192 + w * 1024 + lane * 16;
            load_lds16(gsrc + off, (char*)Ws + off);
        }
        // build M_c [jg][i][e] (writes lane-contiguous)
        {
            int i = t & 63, jg = t >> 6;
            const unsigned char* cr = &cellt[i * 64 + jg * 8];
            __hip_bfloat16* d = &Ms[(jg * 64 + i) * 8];
            #pragma unroll
            for (int e = 0; e < 8; ++e)
                d[e] = __float2bfloat16(cr[e] == c ? 1.0f : 0.0f);
        }
        __syncthreads();                       // D: Ws (vmcnt) + Ms ready

        // Z-phase: Z = Hs(A: row=j,k=h) @ Ws(B: col=ho,k=h), 16 MFMA/wave
        f32x4 z[2][2];
        #pragma unroll
        for (int fm = 0; fm < 2; ++fm)
            #pragma unroll
            for (int fn = 0; fn < 2; ++fn)
                z[fm][fn] = (f32x4){0.f, 0.f, 0.f, 0.f};
        #pragma unroll
        for (int ks = 0; ks < 4; ++ks) {
            int hg = ks * 4 + kg;
            bf16x8 a0 = *(const bf16x8*)&Hs[(hg * 64 + mw * 32 + l15) * 8];
            bf16x8 a1 = *(const bf16x8*)&Hs[(hg * 64 + mw * 32 + 16 + l15) * 8];
            bf16x8 b0 = *(const bf16x8*)&Ws[(hg * 128 + nw * 32 + l15) * 8];
            bf16x8 b1 = *(const bf16x8*)&Ws[(hg * 128 + nw * 32 + 16 + l15) * 8];
            z[0][0] = __builtin_amdgcn_mfma_f32_16x16x32_bf16(a0, b0, z[0][0], 0, 0, 0);
            z[0][1] = __builtin_amdgcn_mfma_f32_16x16x32_bf16(a0, b1, z[0][1], 0, 0, 0);
            z[1][0] = __builtin_amdgcn_mfma_f32_16x16x32_bf16(a1, b0, z[1][0], 0, 0, 0);
            z[1][1] = __builtin_amdgcn_mfma_f32_16x16x32_bf16(a1, b1, z[1][1], 0, 0, 0);
        }
        // pack Z -> Zt [jg][ho][e] bf16 (D: col=l15, row=kg*4+r; writes contiguous)
        #pragma unroll
        for (int fm = 0; fm < 2; ++fm) {
            #pragma unroll
            for (int fn = 0; fn < 2; ++fn) {
                int j0 = mw * 32 + fm * 16 + kg * 4;       // rows j0..j0+3
                int jg = j0 >> 3, e0 = j0 & 7;             // e0 = (kg&1)*4
                int ho = nw * 32 + fn * 16 + l15;
                union { unsigned short us[4]; uint2 v; } pk;
                pk.us[0] = bf16bits(z[fm][fn][0]);
                pk.us[1] = bf16bits(z[fm][fn][1]);
                pk.us[2] = bf16bits(z[fm][fn][2]);
                pk.us[3] = bf16bits(z[fm][fn][3]);
                *(uint2*)((char*)Zt + ((size_t)(jg * 128 + ho) * 8 + e0) * 2) = pk.v;
            }
        }
        __syncthreads();                       // F: Zt ready

        // acc-phase: acc += Ms(A: row=i,k=j) @ Zt(B: col=ho,k=j), 8 MFMA/wave
        #pragma unroll
        for (int ks = 0; ks < 2; ++ks) {
            int jg = ks * 4 + kg;
            bf16x8 a0 = *(const bf16x8*)&Ms[(jg * 64 + mw * 32 + l15) * 8];
            bf16x8 a1 = *(const bf16x8*)&Ms[(jg * 64 + mw * 32 + 16 + l15) * 8];
            bf16x8 b0 = *(const bf16x8*)&Zt[(jg * 128 + nw * 32 + l15) * 8];
            bf16x8 b1 = *(const bf16x8*)&Zt[(jg * 128 + nw * 32 + 16 + l15) * 8];
            acc[0][0] = __builtin_amdgcn_mfma_f32_16x16x32_bf16(a0, b0, acc[0][0], 0, 0, 0);
            acc[0][1] = __builtin_amdgcn_mfma_f32_16x16x32_bf16(a0, b1, acc[0][1], 0, 0, 0);
            acc[1][0] = __builtin_amdgcn_mfma_f32_16x16x32_bf16(a1, b0, acc[1][0], 0, 0, 0);
            acc[1][1] = __builtin_amdgcn_mfma_f32_16x16x32_bf16(a1, b1, acc[1][1], 0, 0, 0);
        }
    }

    // epilogue: partial[chunk][b][i][ho]
    float* pb = partial + (((size_t)chunk * 64 + b) * 64) * 128;
    #pragma unroll
    for (int fm = 0; fm < 2; ++fm)
        #pragma unroll
        for (int fn = 0; fn < 2; ++fn)
            #pragma unroll
            for (int r = 0; r < 4; ++r) {
                int i = mw * 32 + fm * 16 + kg * 4 + r;
                int ho = nw * 32 + fn * 16 + l15;
                pb[(size_t)i * 128 + ho] = acc[fm][fn][r];
            }
}

// ---- reduce: out = bias + sum_chunk partial ----
__global__ __launch_bounds__(512)
void gp_reduce(const float* __restrict__ partial, const float* __restrict__ bias,
               float* __restrict__ out)
{
    int gid = blockIdx.x * 512 + threadIdx.x;  // 131072 float4s
    int ho4 = gid & 31;
    float4 a = *(const float4*)(bias + ho4 * 4);
    #pragma unroll
    for (int ch = 0; ch < NCHUNK; ++ch) {
        float4 v = *(const float4*)(partial + (size_t)ch * 524288 + (size_t)gid * 4);
        a.x += v.x; a.y += v.y; a.z += v.z; a.w += v.w;
    }
    *(float4*)(out + (size_t)gid * 4) = a;
}

extern "C" void kernel_launch(void* const* d_in, const int* in_sizes, int n_in,
                              void* d_out, int out_size, void* d_ws, size_t ws_size,
                              hipStream_t stream)
{
    const float* hid  = (const float*)d_in[0];  // [64,64,128]
    const float* pos  = (const float*)d_in[1];  // [64,64,2]
    const float* W    = (const float*)d_in[2];  // [128,8192]
    const float* bias = (const float*)d_in[3];  // [128]
    float* out = (float*)d_out;

    __hip_bfloat16* Wb = (__hip_bfloat16*)d_ws;                       // 2 MB
    float* partial = (float*)((char*)d_ws + (size_t)2097152);         // 16 MB

    hipLaunchKernelGGL(gp_wconv,  dim3(64),         dim3(512), 0, stream, W, Wb);
    hipLaunchKernelGGL(gp_main,   dim3(NCHUNK * 64), dim3(512), 0, stream, hid, pos, Wb, partial);
    hipLaunchKernelGGL(gp_reduce, dim3(256),        dim3(512), 0, stream, partial, bias, out);
}

// Round 3
// 34.252 us; speedup vs baseline: 1.6992x; 1.0367x over previous
//
#include <hip/hip_runtime.h>
#include <hip/hip_bf16.h>
#include <stdint.h>

// pooled[b,i,:] = bias + sum_{j!=i} W_cell(b,i,j) . hid[b,j,:]
// Fused per (batch, cell-chunk):
//   Z_c  = hid_b (64x128) @ W_c^T (128x128)   A-frags persistent in VGPR,
//                                             B-frags streamed from L2 (no LDS)
//   acc += M_c (64x64, 0/1) @ Z_c             via LDS-packed Zt/Ms (double-buffered)
// One __syncthreads per cell iteration.

typedef __attribute__((ext_vector_type(8))) short bf16x8;
typedef __attribute__((ext_vector_type(4))) float f32x4;

#define NCHUNK 8   // cell chunks -> 64*NCHUNK blocks
#define CPB 8      // cells per block (64/NCHUNK)

__device__ inline unsigned short bf16bits(float x) {
    __hip_bfloat16 h = __float2bfloat16(x);
    return *reinterpret_cast<unsigned short*>(&h);
}

// ---- P1: W f32 [128][8192] -> Wb bf16 [c=64][hg=16][ho=128][e=8] ----
__global__ __launch_bounds__(512)
void gp_wconv(const float* __restrict__ W, __hip_bfloat16* __restrict__ Wb)
{
    __shared__ __attribute__((aligned(16))) __hip_bfloat16 Wl[128][136]; // [ho][h], +8 pad
    const int c = blockIdx.x, t = threadIdx.x;
    #pragma unroll
    for (int q = 0; q < 8; ++q) {
        int flat = q * 512 + t;            // coalesced read of W[:, c*128..+128]
        int ho = flat >> 5, k4 = flat & 31;
        float4 v = *(const float4*)(W + (size_t)ho * 8192 + c * 128 + k4 * 4);
        __hip_bfloat16* d = &Wl[ho][k4 * 4];
        d[0] = __float2bfloat16(v.x); d[1] = __float2bfloat16(v.y);
        d[2] = __float2bfloat16(v.z); d[3] = __float2bfloat16(v.w);
    }
    __syncthreads();
    #pragma unroll
    for (int q = 0; q < 4; ++q) {
        int flat = q * 512 + t;            // flat = hg*128 + ho
        int hg = flat >> 7, ho = flat & 127;
        bf16x8 v = *(const bf16x8*)&Wl[ho][hg * 8];
        *(bf16x8*)(Wb + (size_t)c * 16384 + (size_t)flat * 8) = v; // coalesced
    }
}

// ---- main fused kernel: grid = NCHUNK*64, block = 512 (8 waves) ----
__global__ __launch_bounds__(512, 4)
void gp_main(const float* __restrict__ hid, const float* __restrict__ pos,
             const __hip_bfloat16* __restrict__ Wb, float* __restrict__ partial)
{
    __shared__ __attribute__((aligned(16))) __hip_bfloat16 Hs[16 * 64 * 8];     // [hg][j][e] 16KB
    __shared__ __attribute__((aligned(16))) __hip_bfloat16 Zt[2][8 * 128 * 8];  // [jg][ho][e] 2x16KB
    __shared__ __attribute__((aligned(16))) __hip_bfloat16 Ms[2][8 * 64 * 8];   // [jg][i][e]  2x8KB
    __shared__ unsigned char cellt[64 * 64];                                    // [i][j]      4KB
    __shared__ float ps[128];                                                   // pos[b]

    const int t = threadIdx.x;
    const int b = blockIdx.x & 63, chunk = blockIdx.x >> 6;
    const int w = t >> 6, lane = t & 63;
    const int l15 = lane & 15, kg = lane >> 4;   // 16x16x32 frag: row/col=l15, k-group=kg
    const int mw = w & 1, nw = w >> 1;           // wave tile: rows mw*32.., cols nw*32..

    if (t < 128) ps[t] = pos[(size_t)b * 128 + t];
    __syncthreads();

    // cell table (matches reference: trunc-toward-zero, clip, gx-major)
    #pragma unroll
    for (int q = 0; q < 8; ++q) {
        int idx = q * 512 + t;
        int i = idx >> 6, j = idx & 63;
        float rx = ps[j * 2 + 0] - ps[i * 2 + 0];
        float ry = ps[j * 2 + 1] - ps[i * 2 + 1];
        int gx = (int)((rx + 2.0f) * 2.0f);
        int gy = (int)((ry + 2.0f) * 2.0f);
        gx = gx < 0 ? 0 : (gx > 7 ? 7 : gx);
        gy = gy < 0 ? 0 : (gy > 7 ? 7 : gy);
        cellt[idx] = (i == j) ? 255 : (unsigned char)(gx * 8 + gy);
    }
    // stage hid[b] -> Hs [hg][j][e]
    #pragma unroll
    for (int q = 0; q < 2; ++q) {
        int idx = q * 512 + t;
        int hg = idx >> 6, j = idx & 63;
        const float* src = hid + ((size_t)b * 64 + j) * 128 + hg * 8;
        float4 v0 = *(const float4*)src;
        float4 v1 = *(const float4*)(src + 4);
        __hip_bfloat16* d = &Hs[(hg * 64 + j) * 8];
        d[0] = __float2bfloat16(v0.x); d[1] = __float2bfloat16(v0.y);
        d[2] = __float2bfloat16(v0.z); d[3] = __float2bfloat16(v0.w);
        d[4] = __float2bfloat16(v1.x); d[5] = __float2bfloat16(v1.y);
        d[6] = __float2bfloat16(v1.z); d[7] = __float2bfloat16(v1.w);
    }
    __syncthreads();

    // hoist A-fragments (Hs is static across the c-loop): 8 frags = 32 VGPR
    bf16x8 afr[2][4];
    #pragma unroll
    for (int ks = 0; ks < 4; ++ks) {
        int hg = ks * 4 + kg;
        afr[0][ks] = *(const bf16x8*)&Hs[(hg * 64 + mw * 32 + l15) * 8];
        afr[1][ks] = *(const bf16x8*)&Hs[(hg * 64 + mw * 32 + 16 + l15) * 8];
    }

    f32x4 acc[2][2];
    #pragma unroll
    for (int fm = 0; fm < 2; ++fm)
        #pragma unroll
        for (int fn = 0; fn < 2; ++fn)
            acc[fm][fn] = (f32x4){0.f, 0.f, 0.f, 0.f};

    #pragma unroll 2
    for (int cc = 0; cc < CPB; ++cc) {
        const int p = cc & 1;
        const int c = chunk * CPB + cc;

        // B-fragments straight from L2 (coalesced 256B segments, no LDS)
        const __hip_bfloat16* wc = Wb + (size_t)c * 16384;
        bf16x8 bfr[4][2];
        #pragma unroll
        for (int ks = 0; ks < 4; ++ks) {
            int hg = ks * 4 + kg;
            bfr[ks][0] = *(const bf16x8*)(wc + ((size_t)hg * 128 + nw * 32 + l15) * 8);
            bfr[ks][1] = *(const bf16x8*)(wc + ((size_t)hg * 128 + nw * 32 + 16 + l15) * 8);
        }

        // build M_c [jg][i][e] into ping-pong buffer
        {
            int i = t & 63, jg = t >> 6;
            const unsigned char* cr = &cellt[i * 64 + jg * 8];
            __hip_bfloat16* d = &Ms[p][(jg * 64 + i) * 8];
            #pragma unroll
            for (int e = 0; e < 8; ++e)
                d[e] = __float2bfloat16(cr[e] == c ? 1.0f : 0.0f);
        }

        // Z-phase: pure-register MFMA
        f32x4 z[2][2];
        #pragma unroll
        for (int fm = 0; fm < 2; ++fm)
            #pragma unroll
            for (int fn = 0; fn < 2; ++fn)
                z[fm][fn] = (f32x4){0.f, 0.f, 0.f, 0.f};
        #pragma unroll
        for (int ks = 0; ks < 4; ++ks) {
            z[0][0] = __builtin_amdgcn_mfma_f32_16x16x32_bf16(afr[0][ks], bfr[ks][0], z[0][0], 0, 0, 0);
            z[0][1] = __builtin_amdgcn_mfma_f32_16x16x32_bf16(afr[0][ks], bfr[ks][1], z[0][1], 0, 0, 0);
            z[1][0] = __builtin_amdgcn_mfma_f32_16x16x32_bf16(afr[1][ks], bfr[ks][0], z[1][0], 0, 0, 0);
            z[1][1] = __builtin_amdgcn_mfma_f32_16x16x32_bf16(afr[1][ks], bfr[ks][1], z[1][1], 0, 0, 0);
        }

        // pack Z -> Zt[p] [jg][ho][e] bf16 (D: col=l15, row=kg*4+r)
        #pragma unroll
        for (int fm = 0; fm < 2; ++fm) {
            #pragma unroll
            for (int fn = 0; fn < 2; ++fn) {
                int j0 = mw * 32 + fm * 16 + kg * 4;       // rows j0..j0+3
                int jg = j0 >> 3, e0 = j0 & 7;
                int ho = nw * 32 + fn * 16 + l15;
                union { unsigned short us[4]; uint2 v; } pk;
                pk.us[0] = bf16bits(z[fm][fn][0]);
                pk.us[1] = bf16bits(z[fm][fn][1]);
                pk.us[2] = bf16bits(z[fm][fn][2]);
                pk.us[3] = bf16bits(z[fm][fn][3]);
                *(uint2*)((char*)&Zt[p][0] + ((size_t)(jg * 128 + ho) * 8 + e0) * 2) = pk.v;
            }
        }
        __syncthreads();   // Zt[p] + Ms[p] ready (single barrier per iteration)

        // acc-phase: acc += Ms(A: row=i,k=j) @ Zt(B: col=ho,k=j)
        #pragma unroll
        for (int ks = 0; ks < 2; ++ks) {
            int jg = ks * 4 + kg;
            bf16x8 a0 = *(const bf16x8*)&Ms[p][(jg * 64 + mw * 32 + l15) * 8];
            bf16x8 a1 = *(const bf16x8*)&Ms[p][(jg * 64 + mw * 32 + 16 + l15) * 8];
            bf16x8 b0 = *(const bf16x8*)&Zt[p][(jg * 128 + nw * 32 + l15) * 8];
            bf16x8 b1 = *(const bf16x8*)&Zt[p][(jg * 128 + nw * 32 + 16 + l15) * 8];
            acc[0][0] = __builtin_amdgcn_mfma_f32_16x16x32_bf16(a0, b0, acc[0][0], 0, 0, 0);
            acc[0][1] = __builtin_amdgcn_mfma_f32_16x16x32_bf16(a0, b1, acc[0][1], 0, 0, 0);
            acc[1][0] = __builtin_amdgcn_mfma_f32_16x16x32_bf16(a1, b0, acc[1][0], 0, 0, 0);
            acc[1][1] = __builtin_amdgcn_mfma_f32_16x16x32_bf16(a1, b1, acc[1][1], 0, 0, 0);
        }
    }

    // epilogue: partial[chunk][b][i][ho]
    float* pb = partial + (((size_t)chunk * 64 + b) * 64) * 128;
    #pragma unroll
    for (int fm = 0; fm < 2; ++fm)
        #pragma unroll
        for (int fn = 0; fn < 2; ++fn)
            #pragma unroll
            for (int r = 0; r < 4; ++r) {
                int i = mw * 32 + fm * 16 + kg * 4 + r;
                int ho = nw * 32 + fn * 16 + l15;
                pb[(size_t)i * 128 + ho] = acc[fm][fn][r];
            }
}

// ---- reduce: out = bias + sum_chunk partial ----
__global__ __launch_bounds__(512)
void gp_reduce(const float* __restrict__ partial, const float* __restrict__ bias,
               float* __restrict__ out)
{
    int gid = blockIdx.x * 512 + threadIdx.x;  // 131072 float4s
    int ho4 = gid & 31;
    float4 a = *(const float4*)(bias + ho4 * 4);
    #pragma unroll
    for (int ch = 0; ch < NCHUNK; ++ch) {
        float4 v = *(const float4*)(partial + (size_t)ch * 524288 + (size_t)gid * 4);
        a.x += v.x; a.y += v.y; a.z += v.z; a.w += v.w;
    }
    *(float4*)(out + (size_t)gid * 4) = a;
}

extern "C" void kernel_launch(void* const* d_in, const int* in_sizes, int n_in,
                              void* d_out, int out_size, void* d_ws, size_t ws_size,
                              hipStream_t stream)
{
    const float* hid  = (const float*)d_in[0];  // [64,64,128]
    const float* pos  = (const float*)d_in[1];  // [64,64,2]
    const float* W    = (const float*)d_in[2];  // [128,8192]
    const float* bias = (const float*)d_in[3];  // [128]
    float* out = (float*)d_out;

    __hip_bfloat16* Wb = (__hip_bfloat16*)d_ws;                       // 2 MB
    float* partial = (float*)((char*)d_ws + (size_t)2097152);         // 16 MB

    hipLaunchKernelGGL(gp_wconv,  dim3(64),          dim3(512), 0, stream, W, Wb);
    hipLaunchKernelGGL(gp_main,   dim3(NCHUNK * 64), dim3(512), 0, stream, hid, pos, Wb, partial);
    hipLaunchKernelGGL(gp_reduce, dim3(256),         dim3(512), 0, stream, partial, bias, out);
}